// Round 3
// baseline (783.175 us; speedup 1.0000x reference)
//
#include <hip/hip_runtime.h>

typedef __attribute__((ext_vector_type(4))) float f32x4;
typedef __attribute__((ext_vector_type(16))) float f32x16;
typedef __attribute__((ext_vector_type(4))) unsigned short u16x4;
typedef __attribute__((ext_vector_type(4))) int i32x4;
typedef __attribute__((ext_vector_type(8))) __bf16 bf16x8;

union FragAB {
  u16x4 u[2];
  i32x4 v;
  bf16x8 f;
};

static __device__ __forceinline__ unsigned short f2bf(float x) {
  union { float f; unsigned u; } v;
  v.f = x;
  unsigned r = v.u + 0x7FFFu + ((v.u >> 16) & 1u);  // round-to-nearest-even
  return (unsigned short)(r >> 16);
}

#define NN 8192

// ---------- kernel 1: prep ----------
// (a) adj int32 -> 2-bit pack, BYTE granularity: lane g reads 16 B contiguous
//     (coalesced 1 KB/wave, fixes round-2's stride-64 pattern) and stores 1 byte.
//     Byte gb packs elems [4gb,4gb+4) at bits 2j  == bit-identical to the old
//     dword layout (little-endian), so k_agg's dword/ull reads are unchanged.
// (b) V -> bf16 (Vb, row-major [8192][256])
// (c) W -> bf16 transposed (WbT[(ty*256+n)*256 + k]) for k_transform's B-frags
// (d) out = bias broadcast
__global__ __launch_bounds__(256) void k_prep(
    const int* __restrict__ adj, const float* __restrict__ V,
    const float* __restrict__ w1, const float* __restrict__ w2,
    const float* __restrict__ w3, const float* __restrict__ bias,
    unsigned char* __restrict__ adj2b, unsigned short* __restrict__ Vb,
    unsigned short* __restrict__ WbT, float* __restrict__ out) {
  int t = blockIdx.x * 256 + threadIdx.x;
  int nT = gridDim.x * 256;
  // (a) 67.1M elems -> 16.78M bytes, 32 iters
  for (int g = t; g < 16777216; g += nT) {
    i32x4 a = *(const i32x4*)(adj + (size_t)g * 4);
    adj2b[g] = (unsigned char)((a.x & 3) | ((a.y & 3) << 2) |
                               ((a.z & 3) << 4) | ((a.w & 3) << 6));
  }
  // (b) V: 2.097M f32 -> bf16, 4/lane
  for (int g = t; g < 524288; g += nT) {
    f32x4 f = *(const f32x4*)(V + (size_t)g * 4);
    u16x4 h;
    h.x = f2bf(f.x); h.y = f2bf(f.y); h.z = f2bf(f.z); h.w = f2bf(f.w);
    *(u16x4*)(Vb + (size_t)g * 4) = h;
  }
  // (c) W transpose: per ty, 65536 elems; loads coalesced, 2B scatter stores
  {
    const float* ws_[1];
    for (int e = t; e < 65536; e += nT) {
      int k = e >> 8, n = e & 255;
      WbT[(size_t)(0 * 256 + n) * 256 + k] = f2bf(w1[e]);
    }
    for (int e = t; e < 65536; e += nT) {
      int k = e >> 8, n = e & 255;
      WbT[(size_t)(1 * 256 + n) * 256 + k] = f2bf(w2[e]);
    }
    for (int e = t; e < 65536; e += nT) {
      int k = e >> 8, n = e & 255;
      WbT[(size_t)(2 * 256 + n) * 256 + k] = f2bf(w3[e]);
    }
    (void)ws_;
  }
  // (d) out = bias
  for (int g = t; g < 524288; g += nT) {
    *(f32x4*)(out + (size_t)g * 4) = *(const f32x4*)(bias + ((g * 4) & 255));
  }
}

// ---------- kernel 2: Bp = (V @ Wcat)^T, bf16, LDS-free register GEMM ----------
// Bp element (ty, n, j) at  ty*2097152 + (j>>4)*4096 + n*16 + (j&15)  (verified).
// A-frag (16x16x32): row = lane&15, k = (lane>>4)*8+e  -> direct 16B load from Vb.
// B-frag:            col = lane&15, k = (lane>>4)*8+e  -> direct 16B load from WbT.
// Both mappings are exactly the ones the harness-verified LDS version realized.
// Grid: 128 rb (64-row tiles) x 6 nb (128-col tiles) = 768 blocks, 4 waves,
// wave = 32 rows x 64 cols (mt=2, nt=4). No barriers, no f2bf in the loop.
__global__ __launch_bounds__(256) void k_transform(
    const unsigned short* __restrict__ Vb, const unsigned short* __restrict__ WbT,
    unsigned short* __restrict__ Bp) {
  int bx = blockIdx.x;
  int rb = bx & 127, nb = bx >> 7;
  int tid = threadIdx.x, lane = tid & 63;
  int wv = tid >> 6;
  int wr = wv >> 1, wc = wv & 1;
  int q = lane >> 4, l16 = lane & 15;

  f32x4 acc[2][4];
#pragma unroll
  for (int i = 0; i < 2; i++)
#pragma unroll
    for (int j = 0; j < 4; j++) acc[i][j] = (f32x4)0.0f;

  int r0 = rb * 64 + wr * 32 + l16;        // + mt*16
  int n0 = nb * 128 + wc * 64 + l16;       // + nt*16 (global n in 0..768)
  const unsigned short* av = Vb + (size_t)r0 * 256 + q * 8;
  const unsigned short* bv = WbT + (size_t)n0 * 256 + q * 8;

#pragma unroll 2
  for (int kk = 0; kk < 256; kk += 32) {
    FragAB af[2], bf[4];
#pragma unroll
    for (int mt = 0; mt < 2; mt++)
      af[mt].v = *(const i32x4*)(av + (size_t)(mt * 16) * 256 + kk);
#pragma unroll
    for (int nt = 0; nt < 4; nt++)
      bf[nt].v = *(const i32x4*)(bv + (size_t)(nt * 16) * 256 + kk);
#pragma unroll
    for (int mt = 0; mt < 2; mt++)
#pragma unroll
      for (int nt = 0; nt < 4; nt++)
        acc[mt][nt] = __builtin_amdgcn_mfma_f32_16x16x32_bf16(
            af[mt].f, bf[nt].f, acc[mt][nt], 0, 0, 0);
  }
  // epilogue: D 16x16 layout col = lane&15, row = q*4 + reg (verified)
#pragma unroll
  for (int mt = 0; mt < 2; mt++)
#pragma unroll
    for (int nt = 0; nt < 4; nt++) {
      int n = n0 + nt * 16;                // global 0..767
      int ty = n >> 8, nn = n & 255;
      int j0 = rb * 64 + wr * 32 + mt * 16 + q * 4;
      u16x4 hv;
      hv.x = f2bf(acc[mt][nt].x);
      hv.y = f2bf(acc[mt][nt].y);
      hv.z = f2bf(acc[mt][nt].z);
      hv.w = f2bf(acc[mt][nt].w);
      size_t idx = (size_t)ty * 2097152 + (size_t)(j0 >> 4) * 4096 + nn * 16 + (j0 & 15);
      *(u16x4*)(Bp + idx) = hv;
    }
}

// ---------- kernel 3: out += sum_k (adj==k) @ H_k ----------
// v5: BM=128, BN=256 (full width), BK=32, splitK=8 -> 64x8 = 512 blocks (2/CU).
// 4 waves; wave = 32 rows x 256 cols (nt=8). Per lane per step: ONE adj row ->
// 24 mask dwords (vs 48 in v4) feeding 48 MFMAs (vs 24) -> VALU ~336 cyc vs
// MFMA 384 cyc: the mask build no longer dominates. B tiles double-buffered
// one (kh,ty)-slot ahead (bvA/bvB, statically unrolled) to hide L2 latency.
// ks = bx&7 keeps each XCD's L2 on one Bp k-slice (1.57 MB) + adj2 slice (2 MB).
__global__ __launch_bounds__(256, 2) void k_agg(const unsigned* __restrict__ adj2,
                                                const unsigned short* __restrict__ Bp,
                                                float* __restrict__ out) {
  int bx = blockIdx.x;
  int ks = bx & 7, rb = bx >> 3;
  int tid = threadIdx.x, lane = tid & 63;
  int wv = tid >> 6;  // 0..3: 32-row slab
  int q = lane >> 5, l32 = lane & 31;
  int qsh = q << 4;

  f32x16 acc[8];
#pragma unroll
  for (int nt = 0; nt < 8; nt++) acc[nt] = (f32x16)0.0f;

  int row = rb * 128 + wv * 32 + l32;
  const unsigned* ap = adj2 + (size_t)row * 512 + ks * 64;

  const unsigned short* bp0 = Bp + (size_t)0 * 2097152 + (size_t)ks * 262144 + l32 * 16 + q * 8;
  const unsigned short* bp1 = bp0 + 2097152;
  const unsigned short* bp2 = bp0 + 2 * 2097152;

  unsigned long long c = *(const unsigned long long*)ap;

  FragAB bvA[8], bvB[8];
#pragma unroll
  for (int nt = 0; nt < 8; nt++)  // prologue: slot0 (kh=0,ty=0) -> bvA
    bvA[nt].v = *(const i32x4*)(bp0 + nt * 512);

  for (int step = 0; step < 32; ++step) {
    unsigned long long nx = 0;
    if (step < 31) nx = *(const unsigned long long*)(ap + 2 * (step + 1));
#pragma unroll
    for (int s = 0; s < 6; ++s) {  // slot s = kh*3 + ty
      const int kh = s / 3, ty = s % 3;
      // issue NEXT slot's 8 B-loads into the other buffer
      if (s < 5) {
        const int nkh = (s + 1) / 3, nty = (s + 1) % 3;
        const unsigned short* nbp = (nty == 0) ? bp0 : (nty == 1) ? bp1 : bp2;
#pragma unroll
        for (int nt = 0; nt < 8; nt++) {
          if (s & 1)
            bvA[nt].v = *(const i32x4*)(nbp + nkh * 4096 + nt * 512);
          else
            bvB[nt].v = *(const i32x4*)(nbp + nkh * 4096 + nt * 512);
        }
      } else {  // next step's slot0 (in-bounds: lands within Bp workspace)
#pragma unroll
        for (int nt = 0; nt < 8; nt++) {
          if (s & 1)
            bvA[nt].v = *(const i32x4*)(bp0 + 8192 + nt * 512);
          else
            bvB[nt].v = *(const i32x4*)(bp0 + 8192 + nt * 512);
        }
      }
      // build this slot's A-frag: 4 dwords from this lane's 8 2-bit codes
      unsigned w = (unsigned)(kh ? (c >> 32) : c) >> qsh;
      FragAB A;
#pragma unroll
      for (int d = 0; d < 4; d++) {
        unsigned p0 = (w >> (4 * d)) & 3u, p1 = (w >> (4 * d + 2)) & 3u;
        A.v[d] = (int)((p0 == (unsigned)(ty + 1) ? 0x3F80u : 0u) |
                       (p1 == (unsigned)(ty + 1) ? 0x3F800000u : 0u));
      }
      // 8 MFMAs from the CURRENT buffer (slot parity: even -> bvA)
#pragma unroll
      for (int nt = 0; nt < 8; nt++) {
        if (s & 1)
          acc[nt] = __builtin_amdgcn_mfma_f32_32x32x16_bf16(A.f, bvB[nt].f,
                                                            acc[nt], 0, 0, 0);
        else
          acc[nt] = __builtin_amdgcn_mfma_f32_32x32x16_bf16(A.f, bvA[nt].f,
                                                            acc[nt], 0, 0, 0);
      }
    }
    bp0 += 8192;
    bp1 += 8192;
    bp2 += 8192;
    c = nx;
  }
  // epilogue: C/D 32x32 layout col=lane&31, row=(reg&3)+8*(reg>>2)+4*q
#pragma unroll
  for (int nt = 0; nt < 8; nt++) {
    int col = nt * 32 + l32;
    int rowb = rb * 128 + wv * 32 + 4 * q;
#pragma unroll
    for (int r = 0; r < 16; r++) {
      int orow = rowb + (r & 3) + 8 * (r >> 2);
      atomicAdd(out + (size_t)orow * 256 + col, acc[nt][r]);
    }
  }
}

extern "C" void kernel_launch(void* const* d_in, const int* in_sizes, int n_in,
                              void* d_out, int out_size, void* d_ws,
                              size_t ws_size, hipStream_t stream) {
  const float* V = (const float*)d_in[0];
  const int* adj = (const int*)d_in[1];
  const float* w1 = (const float*)d_in[2];
  const float* w2 = (const float*)d_in[3];
  const float* w3 = (const float*)d_in[4];
  const float* bias = (const float*)d_in[5];
  float* out = (float*)d_out;
  // workspace layout:
  unsigned short* Bp = (unsigned short*)d_ws;                     // 12.58 MB @ 0
  unsigned char* adj2b = (unsigned char*)d_ws + 0xC00000;         // 16 MB
  unsigned short* Vb = (unsigned short*)((char*)d_ws + 0x1C00000);  // 4 MB
  unsigned short* WbT = (unsigned short*)((char*)d_ws + 0x2000000); // 0.375 MB
  // total required: 0x2000000 + 0x60000 = 33.9 MB

  k_prep<<<dim3(2048), dim3(256), 0, stream>>>(adj, V, w1, w2, w3, bias, adj2b,
                                               Vb, WbT, out);
  k_transform<<<dim3(768), dim3(256), 0, stream>>>(Vb, WbT, Bp);
  k_agg<<<dim3(512), dim3(256), 0, stream>>>((const unsigned*)adj2b, Bp, out);
}

// Round 4
// 499.794 us; speedup vs baseline: 1.5670x; 1.5670x over previous
//
#include <hip/hip_runtime.h>

typedef __attribute__((ext_vector_type(4))) float f32x4;
typedef __attribute__((ext_vector_type(16))) float f32x16;
typedef __attribute__((ext_vector_type(4))) unsigned short u16x4;
typedef __attribute__((ext_vector_type(4))) int i32x4;
typedef __attribute__((ext_vector_type(8))) __bf16 bf16x8;

union FragAB {
  u16x4 u[2];
  i32x4 v;
  bf16x8 f;
};

static __device__ __forceinline__ unsigned short f2bf(float x) {
  union { float f; unsigned u; } v;
  v.f = x;
  unsigned r = v.u + 0x7FFFu + ((v.u >> 16) & 1u);  // round-to-nearest-even
  return (unsigned short)(r >> 16);
}

#define NN 8192

// ---------- kernel 1: prep = adj -> 2-bit byte pack + bias broadcast ----------
// Lane g reads 16 B contiguous (coalesced 1 KB/wave) and stores 1 byte.
// Byte g packs adj elems [4g,4g+4) at bits 2j (little-endian identical to the
// dword layout k_agg reads as unsigned/ull).
__global__ __launch_bounds__(256) void k_prep(const int* __restrict__ adj,
                                              const float* __restrict__ bias,
                                              unsigned char* __restrict__ adj2b,
                                              float* __restrict__ out) {
  int t = blockIdx.x * 256 + threadIdx.x;
  int nT = gridDim.x * 256;
  for (int g = t; g < 16777216; g += nT) {
    i32x4 a = *(const i32x4*)(adj + (size_t)g * 4);
    adj2b[g] = (unsigned char)((a.x & 3) | ((a.y & 3) << 2) |
                               ((a.z & 3) << 4) | ((a.w & 3) << 6));
  }
  for (int g = t; g < 524288; g += nT) {
    *(f32x4*)(out + (size_t)g * 4) = *(const f32x4*)(bias + ((g * 4) & 255));
  }
}

// ---------- kernel 2: Bp = (V @ Wcat)^T in k-blocked layout, bf16 ----------
// Round-0 harness-verified version, verbatim.
// Bp element (ty, n, j) at  ty*2097152 + (j>>4)*4096 + n*16 + (j&15).
__global__ __launch_bounds__(256) void k_transform(
    const float* __restrict__ V, const float* __restrict__ w1,
    const float* __restrict__ w2, const float* __restrict__ w3,
    unsigned short* __restrict__ Bp) {
  int bx = blockIdx.x;
  int rb = bx & 63;   // j tile of 128
  int nb = bx >> 6;   // 0..11 (64-wide col tile within 768)
  const float* W = (nb < 4) ? w1 : (nb < 8) ? w2 : w3;
  int nc0 = (nb & 3) * 64;
  int tid = threadIdx.x;
  int lane = tid & 63;
  int wv = tid >> 6;
  int wm = wv >> 1, wn = wv & 1;
  int q = lane >> 4, l16 = lane & 15;

  __shared__ unsigned short tA[128][36];  // V tile bf16, padded (72B rows)
  __shared__ unsigned short tB[64][36];   // W tile transposed [n][c]

  f32x4 acc[4][2];
#pragma unroll
  for (int i = 0; i < 4; i++)
#pragma unroll
    for (int j = 0; j < 2; j++) acc[i][j] = (f32x4)0.0f;

  for (int kk = 0; kk < 256; kk += 32) {
    {
      int r = tid >> 1, c0 = (tid & 1) * 16;
      const float* src = V + (size_t)(rb * 128 + r) * 256 + kk + c0;
      f32x4 f0 = *(const f32x4*)(src + 0);
      f32x4 f1 = *(const f32x4*)(src + 4);
      f32x4 f2 = *(const f32x4*)(src + 8);
      f32x4 f3 = *(const f32x4*)(src + 12);
      unsigned short* d = &tA[r][c0];
      d[0] = f2bf(f0.x);  d[1] = f2bf(f0.y);  d[2] = f2bf(f0.z);  d[3] = f2bf(f0.w);
      d[4] = f2bf(f1.x);  d[5] = f2bf(f1.y);  d[6] = f2bf(f1.z);  d[7] = f2bf(f1.w);
      d[8] = f2bf(f2.x);  d[9] = f2bf(f2.y);  d[10] = f2bf(f2.z); d[11] = f2bf(f2.w);
      d[12] = f2bf(f3.x); d[13] = f2bf(f3.y); d[14] = f2bf(f3.z); d[15] = f2bf(f3.w);
    }
    {
      int r = tid >> 3, c0 = (tid & 7) * 8;
      const float* src = W + (size_t)(kk + r) * 256 + nc0 + c0;
      f32x4 g0 = *(const f32x4*)(src);
      f32x4 g1 = *(const f32x4*)(src + 4);
      tB[c0 + 0][r] = f2bf(g0.x); tB[c0 + 1][r] = f2bf(g0.y);
      tB[c0 + 2][r] = f2bf(g0.z); tB[c0 + 3][r] = f2bf(g0.w);
      tB[c0 + 4][r] = f2bf(g1.x); tB[c0 + 5][r] = f2bf(g1.y);
      tB[c0 + 6][r] = f2bf(g1.z); tB[c0 + 7][r] = f2bf(g1.w);
    }
    __syncthreads();
    FragAB af[4], bf[2];
#pragma unroll
    for (int mt = 0; mt < 4; mt++) {
      const unsigned short* p = &tA[wm * 64 + mt * 16 + l16][q * 8];
      af[mt].u[0] = *(const u16x4*)p;
      af[mt].u[1] = *(const u16x4*)(p + 4);
    }
#pragma unroll
    for (int nt = 0; nt < 2; nt++) {
      const unsigned short* p = &tB[wn * 32 + nt * 16 + l16][q * 8];
      bf[nt].u[0] = *(const u16x4*)p;
      bf[nt].u[1] = *(const u16x4*)(p + 4);
    }
#pragma unroll
    for (int mt = 0; mt < 4; mt++)
#pragma unroll
      for (int nt = 0; nt < 2; nt++)
        acc[mt][nt] = __builtin_amdgcn_mfma_f32_16x16x32_bf16(
            af[mt].f, bf[nt].f, acc[mt][nt], 0, 0, 0);
    __syncthreads();
  }
  int ty = nb >> 2;
#pragma unroll
  for (int mt = 0; mt < 4; mt++)
#pragma unroll
    for (int nt = 0; nt < 2; nt++) {
      int n = (nb & 3) * 64 + wn * 32 + nt * 16 + l16;
      int j0 = rb * 128 + wm * 64 + mt * 16 + q * 4;
      u16x4 hv;
      hv.x = f2bf(acc[mt][nt].x);
      hv.y = f2bf(acc[mt][nt].y);
      hv.z = f2bf(acc[mt][nt].z);
      hv.w = f2bf(acc[mt][nt].w);
      size_t idx = (size_t)ty * 2097152 + (size_t)(j0 >> 4) * 4096 + n * 16 + (j0 & 15);
      *(u16x4*)(Bp + idx) = hv;
    }
}

// ---------- kernel 3: out += sum_k (adj==k) @ H_k ----------
// v6 = v4's proven structure (batch loads, 1-step adj reg-prefetch, no barriers,
// no LDS) with wave reshaped to 64 rows x 128 cols (mt=2, nt=4), BN=256/block.
// Same L2 volume as v4 (rows/wave=64 -> 1.6 GB total), but 48 MFMA per
// wave-step against the same 48 mask-dwords -> mask VALU per MFMA halved.
// Two 12-load batches per step (kh halves); each batch's L2 latency hides
// under the other half's mask-build + MFMAs. 6 advancing [ty][kh] pointers
// make every B-load a pure imm-offset (nt*1024 B <= 3072 < 4096).
// Grid 64 rb x 8 ks = 512 blocks (2/CU); ks = bx&7 -> per-XCD L2 k-slice.
__global__ __launch_bounds__(256, 2) void k_agg(const unsigned* __restrict__ adj2,
                                                const unsigned short* __restrict__ Bp,
                                                float* __restrict__ out) {
  int bx = blockIdx.x;
  int ks = bx & 7, rb = bx >> 3;
  int tid = threadIdx.x, lane = tid & 63;
  int wv = tid >> 6;
  int wm = wv >> 1, wn = wv & 1;  // wm: 64-row slab, wn: 128-col slab
  int q = lane >> 5, l32 = lane & 31;
  int qsh = q << 4;

  f32x16 acc[2][4];
#pragma unroll
  for (int mt = 0; mt < 2; mt++)
#pragma unroll
    for (int nt = 0; nt < 4; nt++) acc[mt][nt] = (f32x16)0.0f;

  // adj2 rows for this lane's two 32-row MFMA slabs
  int r0 = rb * 128 + wm * 64 + l32;
  const unsigned* ap0 = adj2 + (size_t)r0 * 512 + ks * 64;
  const unsigned* ap1 = ap0 + 32 * 512;

  // 6 B-pointers [ty][kh]; elem = ty*2097152 + (ks*64+kh)*4096 + n*16 + q*8
  int nbase = (wn * 128 + l32) * 16 + q * 8;
  const unsigned short* bb[3][2];
#pragma unroll
  for (int ty = 0; ty < 3; ty++)
#pragma unroll
    for (int kh = 0; kh < 2; kh++)
      bb[ty][kh] = Bp + (size_t)ty * 2097152 + ((size_t)ks * 64 + kh) * 4096 + nbase;

  unsigned long long c0 = *(const unsigned long long*)ap0;
  unsigned long long c1 = *(const unsigned long long*)ap1;

  for (int step = 0; step < 32; ++step) {
    unsigned long long nx0 = 0, nx1 = 0;
    if (step < 31) {  // next step's adj codes (imm-offset loads)
      nx0 = *(const unsigned long long*)(ap0 + 2 * (step + 1));
      nx1 = *(const unsigned long long*)(ap1 + 2 * (step + 1));
    }
    // ---- batch kh=0: 12 B loads (imm offsets), then masks+MFMAs ----
    FragAB bv0[3][4];
#pragma unroll
    for (int ty = 0; ty < 3; ty++)
#pragma unroll
      for (int nt = 0; nt < 4; nt++)
        bv0[ty][nt].v = *(const i32x4*)(bb[ty][0] + nt * 512);
    {
      unsigned w0 = (unsigned)c0 >> qsh;
      unsigned w1 = (unsigned)c1 >> qsh;
#pragma unroll
      for (int ty = 0; ty < 3; ty++) {
        FragAB A0, A1;
#pragma unroll
        for (int d = 0; d < 4; d++) {
          unsigned p00 = (w0 >> (4 * d)) & 3u, p01 = (w0 >> (4 * d + 2)) & 3u;
          unsigned p10 = (w1 >> (4 * d)) & 3u, p11 = (w1 >> (4 * d + 2)) & 3u;
          A0.v[d] = (int)((p00 == (unsigned)(ty + 1) ? 0x3F80u : 0u) |
                          (p01 == (unsigned)(ty + 1) ? 0x3F800000u : 0u));
          A1.v[d] = (int)((p10 == (unsigned)(ty + 1) ? 0x3F80u : 0u) |
                          (p11 == (unsigned)(ty + 1) ? 0x3F800000u : 0u));
        }
#pragma unroll
        for (int nt = 0; nt < 4; nt++) {
          acc[0][nt] = __builtin_amdgcn_mfma_f32_32x32x16_bf16(
              A0.f, bv0[ty][nt].f, acc[0][nt], 0, 0, 0);
          acc[1][nt] = __builtin_amdgcn_mfma_f32_32x32x16_bf16(
              A1.f, bv0[ty][nt].f, acc[1][nt], 0, 0, 0);
        }
      }
    }
    // ---- batch kh=1 ----
    FragAB bv1[3][4];
#pragma unroll
    for (int ty = 0; ty < 3; ty++)
#pragma unroll
      for (int nt = 0; nt < 4; nt++)
        bv1[ty][nt].v = *(const i32x4*)(bb[ty][1] + nt * 512);
    {
      unsigned w0 = (unsigned)(c0 >> 32) >> qsh;
      unsigned w1 = (unsigned)(c1 >> 32) >> qsh;
#pragma unroll
      for (int ty = 0; ty < 3; ty++) {
        FragAB A0, A1;
#pragma unroll
        for (int d = 0; d < 4; d++) {
          unsigned p00 = (w0 >> (4 * d)) & 3u, p01 = (w0 >> (4 * d + 2)) & 3u;
          unsigned p10 = (w1 >> (4 * d)) & 3u, p11 = (w1 >> (4 * d + 2)) & 3u;
          A0.v[d] = (int)((p00 == (unsigned)(ty + 1) ? 0x3F80u : 0u) |
                          (p01 == (unsigned)(ty + 1) ? 0x3F800000u : 0u));
          A1.v[d] = (int)((p10 == (unsigned)(ty + 1) ? 0x3F80u : 0u) |
                          (p11 == (unsigned)(ty + 1) ? 0x3F800000u : 0u));
        }
#pragma unroll
        for (int nt = 0; nt < 4; nt++) {
          acc[0][nt] = __builtin_amdgcn_mfma_f32_32x32x16_bf16(
              A0.f, bv1[ty][nt].f, acc[0][nt], 0, 0, 0);
          acc[1][nt] = __builtin_amdgcn_mfma_f32_32x32x16_bf16(
              A1.f, bv1[ty][nt].f, acc[1][nt], 0, 0, 0);
        }
      }
    }
    // advance pointers one step (16384 B)
#pragma unroll
    for (int ty = 0; ty < 3; ty++)
#pragma unroll
      for (int kh = 0; kh < 2; kh++) bb[ty][kh] += 8192;
    c0 = nx0;
    c1 = nx1;
  }
  // epilogue: C/D 32x32 layout col=lane&31, row=(reg&3)+8*(reg>>2)+4*q
#pragma unroll
  for (int mt = 0; mt < 2; mt++)
#pragma unroll
    for (int nt = 0; nt < 4; nt++) {
      int col = wn * 128 + nt * 32 + l32;
      int rowb = rb * 128 + wm * 64 + mt * 32 + 4 * q;
#pragma unroll
      for (int r = 0; r < 16; r++) {
        int row = rowb + (r & 3) + 8 * (r >> 2);
        atomicAdd(out + (size_t)row * 256 + col, acc[mt][nt][r]);
      }
    }
}

extern "C" void kernel_launch(void* const* d_in, const int* in_sizes, int n_in,
                              void* d_out, int out_size, void* d_ws,
                              size_t ws_size, hipStream_t stream) {
  const float* V = (const float*)d_in[0];
  const int* adj = (const int*)d_in[1];
  const float* w1 = (const float*)d_in[2];
  const float* w2 = (const float*)d_in[3];
  const float* w3 = (const float*)d_in[4];
  const float* bias = (const float*)d_in[5];
  float* out = (float*)d_out;
  unsigned short* Bp = (unsigned short*)d_ws;              // 12.58 MB @ 0
  unsigned char* adj2b = (unsigned char*)d_ws + 0xC00000;  // 16 MB
  // workspace requirement: 0xC00000 + 0x1000000 = 29,360,128 bytes

  k_prep<<<dim3(2048), dim3(256), 0, stream>>>(adj, bias, adj2b, out);
  k_transform<<<dim3(768), dim3(256), 0, stream>>>(V, w1, w2, w3, Bp);
  k_agg<<<dim3(512), dim3(256), 0, stream>>>((const unsigned*)adj2b, Bp, out);
}

// Round 5
// 499.712 us; speedup vs baseline: 1.5673x; 1.0002x over previous
//
#include <hip/hip_runtime.h>

typedef __attribute__((ext_vector_type(4))) float f32x4;
typedef __attribute__((ext_vector_type(16))) float f32x16;
typedef __attribute__((ext_vector_type(4))) unsigned short u16x4;
typedef __attribute__((ext_vector_type(4))) int i32x4;
typedef __attribute__((ext_vector_type(8))) __bf16 bf16x8;

union FragAB {
  u16x4 u[2];
  i32x4 v;
  bf16x8 f;
};

static __device__ __forceinline__ unsigned short f2bf(float x) {
  union { float f; unsigned u; } v;
  v.f = x;
  unsigned r = v.u + 0x7FFFu + ((v.u >> 16) & 1u);  // round-to-nearest-even
  return (unsigned short)(r >> 16);
}

#define NN 8192

// ---------- kernel 1: prep ----------
// (a) adj -> 2-bit byte pack (coalesced 16B reads, 1B stores) [verified]
// (b) V  -> Vbp  k-blocked bf16:  idx = (k>>3)*65536 + row*8 + (k&7)
//     so a 16x16x32 A-frag load (lane=row l16, k=q*8+e) is ONE 16B load,
//     256B-contiguous across 16 lanes.
// (c) W  -> Wbp  k-blocked bf16:  idx = (k>>3)*6144 + (ty*256+n)*8 + (k&7)
// (d) out = bias broadcast
__global__ __launch_bounds__(256) void k_prep(
    const int* __restrict__ adj, const float* __restrict__ V,
    const float* __restrict__ w1, const float* __restrict__ w2,
    const float* __restrict__ w3, const float* __restrict__ bias,
    unsigned char* __restrict__ adj2b, unsigned short* __restrict__ Vbp,
    unsigned short* __restrict__ Wbp, float* __restrict__ out) {
  int t = blockIdx.x * 256 + threadIdx.x;
  int nT = gridDim.x * 256;
  // (a)
  for (int g = t; g < 16777216; g += nT) {
    i32x4 a = *(const i32x4*)(adj + (size_t)g * 4);
    adj2b[g] = (unsigned char)((a.x & 3) | ((a.y & 3) << 2) |
                               ((a.z & 3) << 4) | ((a.w & 3) << 6));
  }
  // (b) 2.097M f32, 4 per thread-iter; dst 8B-aligned
  for (int g = t; g < 524288; g += nT) {
    int f = g * 4;
    int row = f >> 8, kcol = f & 255;
    f32x4 x = *(const f32x4*)(V + (size_t)f);
    u16x4 h;
    h.x = f2bf(x.x); h.y = f2bf(x.y); h.z = f2bf(x.z); h.w = f2bf(x.w);
    *(u16x4*)(Vbp + (size_t)(kcol >> 3) * 65536 + (size_t)row * 8 + (kcol & 7)) = h;
  }
  // (c) 3 x 65536 elems; coalesced loads, 2B scatter stores (0.375 MB total)
  for (int e = t; e < 65536; e += nT) {
    int k = e >> 8, n = e & 255;
    Wbp[(size_t)(k >> 3) * 6144 + (size_t)(0 * 256 + n) * 8 + (k & 7)] = f2bf(w1[e]);
  }
  for (int e = t; e < 65536; e += nT) {
    int k = e >> 8, n = e & 255;
    Wbp[(size_t)(k >> 3) * 6144 + (size_t)(1 * 256 + n) * 8 + (k & 7)] = f2bf(w2[e]);
  }
  for (int e = t; e < 65536; e += nT) {
    int k = e >> 8, n = e & 255;
    Wbp[(size_t)(k >> 3) * 6144 + (size_t)(2 * 256 + n) * 8 + (k & 7)] = f2bf(w3[e]);
  }
  // (d)
  for (int g = t; g < 524288; g += nT) {
    *(f32x4*)(out + (size_t)g * 4) = *(const f32x4*)(bias + ((g * 4) & 255));
  }
}

// ---------- kernel 2: Bp = (V @ Wcat)^T, pure-register GEMM, v3 ----------
// Structure/mapping = round-3 verified reg-GEMM; inputs now k-blocked so every
// frag load is coalesced (16 lanes x 16B = 256B segments). No LDS, no barriers,
// no f2bf in the loop. Grid: 128 rb (64-row) x 6 nb (128-col) = 768 blocks,
// 4 waves, wave = 32 rows x 64 cols (mt=2, nt=4).
// Bp element (ty, n, j) at  ty*2097152 + (j>>4)*4096 + n*16 + (j&15)  [verified].
__global__ __launch_bounds__(256) void k_transform(
    const unsigned short* __restrict__ Vbp, const unsigned short* __restrict__ Wbp,
    unsigned short* __restrict__ Bp) {
  int bx = blockIdx.x;
  int rb = bx & 127, nb = bx >> 7;
  int tid = threadIdx.x, lane = tid & 63;
  int wv = tid >> 6;
  int wr = wv >> 1, wc = wv & 1;
  int q = lane >> 4, l16 = lane & 15;

  f32x4 acc[2][4];
#pragma unroll
  for (int i = 0; i < 2; i++)
#pragma unroll
    for (int j = 0; j < 4; j++) acc[i][j] = (f32x4)0.0f;

  int r0 = rb * 64 + wr * 32 + l16;        // + mt*16
  int n0 = nb * 128 + wc * 64 + l16;       // + nt*16 (global n in 0..768)
  // frag base: k-block (kk>>3)+q, elem row*8 / n*8
  const unsigned short* av = Vbp + (size_t)q * 65536 + (size_t)r0 * 8;
  const unsigned short* bv = Wbp + (size_t)q * 6144 + (size_t)n0 * 8;

#pragma unroll 2
  for (int kk = 0; kk < 256; kk += 32) {
    FragAB af[2], bf[4];
#pragma unroll
    for (int mt = 0; mt < 2; mt++)
      af[mt].v = *(const i32x4*)(av + (size_t)(kk >> 3) * 65536 + mt * 128);
#pragma unroll
    for (int nt = 0; nt < 4; nt++)
      bf[nt].v = *(const i32x4*)(bv + (size_t)(kk >> 3) * 6144 + nt * 128);
#pragma unroll
    for (int mt = 0; mt < 2; mt++)
#pragma unroll
      for (int nt = 0; nt < 4; nt++)
        acc[mt][nt] = __builtin_amdgcn_mfma_f32_16x16x32_bf16(
            af[mt].f, bf[nt].f, acc[mt][nt], 0, 0, 0);
  }
  // epilogue: D 16x16 layout col = lane&15, row = q*4 + reg [verified]
#pragma unroll
  for (int mt = 0; mt < 2; mt++)
#pragma unroll
    for (int nt = 0; nt < 4; nt++) {
      int n = n0 + nt * 16;                // global 0..767
      int ty = n >> 8, nn = n & 255;
      int j0 = rb * 64 + wr * 32 + mt * 16 + q * 4;
      u16x4 hv;
      hv.x = f2bf(acc[mt][nt].x);
      hv.y = f2bf(acc[mt][nt].y);
      hv.z = f2bf(acc[mt][nt].z);
      hv.w = f2bf(acc[mt][nt].w);
      size_t idx = (size_t)ty * 2097152 + (size_t)(j0 >> 4) * 4096 + nn * 16 + (j0 & 15);
      *(u16x4*)(Bp + idx) = hv;
    }
}

// ---------- kernel 3: out += sum_k (adj==k) @ H_k  (v6, unchanged) ----------
// Batch loads, 1-step adj reg-prefetch, no barriers, no LDS. Wave = 64 rows x
// 128 cols (mt=2, nt=4), BN=256/block. Two 12-load batches per step (kh halves).
// Grid 64 rb x 8 ks = 512 blocks (2/CU); ks = bx&7 -> per-XCD L2 k-slice.
__global__ __launch_bounds__(256, 2) void k_agg(const unsigned* __restrict__ adj2,
                                                const unsigned short* __restrict__ Bp,
                                                float* __restrict__ out) {
  int bx = blockIdx.x;
  int ks = bx & 7, rb = bx >> 3;
  int tid = threadIdx.x, lane = tid & 63;
  int wv = tid >> 6;
  int wm = wv >> 1, wn = wv & 1;  // wm: 64-row slab, wn: 128-col slab
  int q = lane >> 5, l32 = lane & 31;
  int qsh = q << 4;

  f32x16 acc[2][4];
#pragma unroll
  for (int mt = 0; mt < 2; mt++)
#pragma unroll
    for (int nt = 0; nt < 4; nt++) acc[mt][nt] = (f32x16)0.0f;

  int r0 = rb * 128 + wm * 64 + l32;
  const unsigned* ap0 = adj2 + (size_t)r0 * 512 + ks * 64;
  const unsigned* ap1 = ap0 + 32 * 512;

  int nbase = (wn * 128 + l32) * 16 + q * 8;
  const unsigned short* bb[3][2];
#pragma unroll
  for (int ty = 0; ty < 3; ty++)
#pragma unroll
    for (int kh = 0; kh < 2; kh++)
      bb[ty][kh] = Bp + (size_t)ty * 2097152 + ((size_t)ks * 64 + kh) * 4096 + nbase;

  unsigned long long c0 = *(const unsigned long long*)ap0;
  unsigned long long c1 = *(const unsigned long long*)ap1;

  for (int step = 0; step < 32; ++step) {
    unsigned long long nx0 = 0, nx1 = 0;
    if (step < 31) {
      nx0 = *(const unsigned long long*)(ap0 + 2 * (step + 1));
      nx1 = *(const unsigned long long*)(ap1 + 2 * (step + 1));
    }
    // ---- batch kh=0 ----
    FragAB bv0[3][4];
#pragma unroll
    for (int ty = 0; ty < 3; ty++)
#pragma unroll
      for (int nt = 0; nt < 4; nt++)
        bv0[ty][nt].v = *(const i32x4*)(bb[ty][0] + nt * 512);
    {
      unsigned w0 = (unsigned)c0 >> qsh;
      unsigned w1 = (unsigned)c1 >> qsh;
#pragma unroll
      for (int ty = 0; ty < 3; ty++) {
        FragAB A0, A1;
#pragma unroll
        for (int d = 0; d < 4; d++) {
          unsigned p00 = (w0 >> (4 * d)) & 3u, p01 = (w0 >> (4 * d + 2)) & 3u;
          unsigned p10 = (w1 >> (4 * d)) & 3u, p11 = (w1 >> (4 * d + 2)) & 3u;
          A0.v[d] = (int)((p00 == (unsigned)(ty + 1) ? 0x3F80u : 0u) |
                          (p01 == (unsigned)(ty + 1) ? 0x3F800000u : 0u));
          A1.v[d] = (int)((p10 == (unsigned)(ty + 1) ? 0x3F80u : 0u) |
                          (p11 == (unsigned)(ty + 1) ? 0x3F800000u : 0u));
        }
#pragma unroll
        for (int nt = 0; nt < 4; nt++) {
          acc[0][nt] = __builtin_amdgcn_mfma_f32_32x32x16_bf16(
              A0.f, bv0[ty][nt].f, acc[0][nt], 0, 0, 0);
          acc[1][nt] = __builtin_amdgcn_mfma_f32_32x32x16_bf16(
              A1.f, bv0[ty][nt].f, acc[1][nt], 0, 0, 0);
        }
      }
    }
    // ---- batch kh=1 ----
    FragAB bv1[3][4];
#pragma unroll
    for (int ty = 0; ty < 3; ty++)
#pragma unroll
      for (int nt = 0; nt < 4; nt++)
        bv1[ty][nt].v = *(const i32x4*)(bb[ty][1] + nt * 512);
    {
      unsigned w0 = (unsigned)(c0 >> 32) >> qsh;
      unsigned w1 = (unsigned)(c1 >> 32) >> qsh;
#pragma unroll
      for (int ty = 0; ty < 3; ty++) {
        FragAB A0, A1;
#pragma unroll
        for (int d = 0; d < 4; d++) {
          unsigned p00 = (w0 >> (4 * d)) & 3u, p01 = (w0 >> (4 * d + 2)) & 3u;
          unsigned p10 = (w1 >> (4 * d)) & 3u, p11 = (w1 >> (4 * d + 2)) & 3u;
          A0.v[d] = (int)((p00 == (unsigned)(ty + 1) ? 0x3F80u : 0u) |
                          (p01 == (unsigned)(ty + 1) ? 0x3F800000u : 0u));
          A1.v[d] = (int)((p10 == (unsigned)(ty + 1) ? 0x3F80u : 0u) |
                          (p11 == (unsigned)(ty + 1) ? 0x3F800000u : 0u));
        }
#pragma unroll
        for (int nt = 0; nt < 4; nt++) {
          acc[0][nt] = __builtin_amdgcn_mfma_f32_32x32x16_bf16(
              A0.f, bv1[ty][nt].f, acc[0][nt], 0, 0, 0);
          acc[1][nt] = __builtin_amdgcn_mfma_f32_32x32x16_bf16(
              A1.f, bv1[ty][nt].f, acc[1][nt], 0, 0, 0);
        }
      }
    }
#pragma unroll
    for (int ty = 0; ty < 3; ty++)
#pragma unroll
      for (int kh = 0; kh < 2; kh++) bb[ty][kh] += 8192;
    c0 = nx0;
    c1 = nx1;
  }
  // epilogue: C/D 32x32 layout col=lane&31, row=(reg&3)+8*(reg>>2)+4*q
#pragma unroll
  for (int mt = 0; mt < 2; mt++)
#pragma unroll
    for (int nt = 0; nt < 4; nt++) {
      int col = wn * 128 + nt * 32 + l32;
      int rowb = rb * 128 + wm * 64 + mt * 32 + 4 * q;
#pragma unroll
      for (int r = 0; r < 16; r++) {
        int row = rowb + (r & 3) + 8 * (r >> 2);
        atomicAdd(out + (size_t)row * 256 + col, acc[mt][nt][r]);
      }
    }
}

extern "C" void kernel_launch(void* const* d_in, const int* in_sizes, int n_in,
                              void* d_out, int out_size, void* d_ws,
                              size_t ws_size, hipStream_t stream) {
  const float* V = (const float*)d_in[0];
  const int* adj = (const int*)d_in[1];
  const float* w1 = (const float*)d_in[2];
  const float* w2 = (const float*)d_in[3];
  const float* w3 = (const float*)d_in[4];
  const float* bias = (const float*)d_in[5];
  float* out = (float*)d_out;
  // workspace layout:
  unsigned short* Bp = (unsigned short*)d_ws;                       // 12.58 MB @ 0
  unsigned char* adj2b = (unsigned char*)d_ws + 0xC00000;           // 16 MB
  unsigned short* Vbp = (unsigned short*)((char*)d_ws + 0x1C00000); // 4 MB
  unsigned short* Wbp = (unsigned short*)((char*)d_ws + 0x2000000); // 0.375 MB
  // total required: 0x2060000 = 33.9 MB (fits prior-verified allocation)

  k_prep<<<dim3(2048), dim3(256), 0, stream>>>(adj, V, w1, w2, w3, bias, adj2b,
                                               Vbp, Wbp, out);
  k_transform<<<dim3(768), dim3(256), 0, stream>>>(Vbp, Wbp, Bp);
  k_agg<<<dim3(512), dim3(256), 0, stream>>>((const unsigned*)adj2b, Bp, out);
}